// Round 2
// baseline (609.697 us; speedup 1.0000x reference)
//
#include <hip/hip_runtime.h>
#include <hip/hip_bf16.h>

#define NFREQ 50
#define EMBD  10

// sin/cos of x (radians) via HW v_sin/v_cos. HW takes revolutions; reduce
// into [0,1) with v_fract first (exact by periodicity).
__device__ __forceinline__ void fast_sincos2pi(float x, float& s, float& c) {
    float r = x * 0.15915494309189535f;       // x / (2*pi)
    r = __builtin_amdgcn_fractf(r);           // [0,1): safe domain
    s = __builtin_amdgcn_sinf(r);             // sin(2*pi*r)
    c = __builtin_amdgcn_cosf(r);             // cos(2*pi*r)
}

__global__ void zero_ws(float4* p, int n4) {
    int t = blockIdx.x * blockDim.x + threadIdx.x;
    float4 z = make_float4(0.f, 0.f, 0.f, 0.f);
    for (int i = t; i < n4; i += gridDim.x * blockDim.x) p[i] = z;
}

__global__ __launch_bounds__(256) void frag_kernel(
    const float2* __restrict__ coords, const int* __restrict__ cgix,
    const float* __restrict__ W1, const float* __restrict__ b1,
    const float* __restrict__ W2, const float* __restrict__ b2,
    float* __restrict__ pooled, int n)
{
    int t = blockIdx.x * blockDim.x + threadIdx.x;
    if (t >= n) return;
    float2 cc = coords[t];
    int seg = cgix[t];

    float acc[EMBD];
    #pragma unroll
    for (int j = 0; j < EMBD; ++j) acc[j] = b1[j];

    // enc[d*100 + 2i]   = sin(c_d * f_{i+1})
    // enc[d*100 + 2i+1] = cos(c_d * f_{i+1}),  f_m = 1000^(-2m/50)
    #pragma unroll
    for (int d = 0; d < 2; ++d) {
        float cd = d ? cc.y : cc.x;
        #pragma unroll
        for (int i = 0; i < NFREQ; ++i) {
            // 1000^(-2(i+1)/50) = 2^(-(i+1)*2*log2(1000)/50); folds to a literal
            float f = __builtin_exp2f(-0.39863137138648348f * (float)(i + 1));
            float s, co;
            fast_sincos2pi(cd * f, s, co);
            const float* w = W1 + (d * 2 * NFREQ + 2 * i) * EMBD;  // uniform -> s_load
            #pragma unroll
            for (int j = 0; j < EMBD; ++j) acc[j] = fmaf(s,  w[j],        acc[j]);
            #pragma unroll
            for (int j = 0; j < EMBD; ++j) acc[j] = fmaf(co, w[EMBD + j], acc[j]);
        }
    }

    // sigmoid
    float h[EMBD];
    #pragma unroll
    for (int j = 0; j < EMBD; ++j)
        h[j] = __builtin_amdgcn_rcpf(1.0f + __expf(-acc[j]));

    // layer 2: emb = h @ W2 + b2
    float e[EMBD];
    #pragma unroll
    for (int j = 0; j < EMBD; ++j) e[j] = b2[j];
    #pragma unroll
    for (int m = 0; m < EMBD; ++m) {
        #pragma unroll
        for (int j = 0; j < EMBD; ++j) e[j] = fmaf(h[m], W2[m * EMBD + j], e[j]);
    }

    // segment-sum via atomics (sorted idx, avg 4 frags/segment -> low contention)
    float* p = pooled + (long)seg * EMBD;
    #pragma unroll
    for (int j = 0; j < EMBD; ++j) atomicAdd(p + j, e[j]);
}

__global__ __launch_bounds__(256) void expr_kernel(
    const float* __restrict__ pooled,
    const float* __restrict__ We1, const float* __restrict__ be1,
    const float* __restrict__ We2, const float* __restrict__ be2,
    float* __restrict__ out, int nseg)
{
    int t = blockIdx.x * blockDim.x + threadIdx.x;
    if (t >= nseg) return;
    const float* p = pooled + (long)t * EMBD;
    float x[EMBD];
    #pragma unroll
    for (int j = 0; j < EMBD; ++j) x[j] = p[j];
    float o = be2[0];
    #pragma unroll
    for (int j = 0; j < EMBD; ++j) {
        float a = be1[j];
        #pragma unroll
        for (int m = 0; m < EMBD; ++m) a = fmaf(x[m], We1[m * EMBD + j], a);
        float hj = __builtin_amdgcn_rcpf(1.0f + __expf(-a));
        o = fmaf(hj, We2[j], o);
    }
    out[t] = o;   // reference output dtype is float32
}

extern "C" void kernel_launch(void* const* d_in, const int* in_sizes, int n_in,
                              void* d_out, int out_size, void* d_ws, size_t ws_size,
                              hipStream_t stream) {
    const float2* coords = (const float2*)d_in[0];
    const int*    cgix   = (const int*)d_in[1];
    const float*  W1     = (const float*)d_in[4];
    const float*  b1     = (const float*)d_in[5];
    const float*  W2     = (const float*)d_in[6];
    const float*  b2     = (const float*)d_in[7];
    const float*  We1    = (const float*)d_in[8];
    const float*  be1    = (const float*)d_in[9];
    const float*  We2    = (const float*)d_in[10];
    const float*  be2    = (const float*)d_in[11];
    float*        out    = (float*)d_out;

    int n    = in_sizes[0] / 2;      // 1,000,000 fragments
    int nseg = out_size;             // 250,000 = cells*genes
    float* pooled = (float*)d_ws;    // nseg*10 f32 = 10 MB scratch

    // ws is poisoned (0xAA) and not re-poisoned between replays: zero every call
    int n4 = (nseg * EMBD) / 4;      // 2.5M floats, divisible by 4
    zero_ws<<<1024, 256, 0, stream>>>((float4*)pooled, n4);

    frag_kernel<<<(n + 255) / 256, 256, 0, stream>>>(coords, cgix, W1, b1, W2, b2,
                                                     pooled, n);
    expr_kernel<<<(nseg + 255) / 256, 256, 0, stream>>>(pooled, We1, be1, We2, be2,
                                                        out, nseg);
}

// Round 3
// 92.368 us; speedup vs baseline: 6.6007x; 6.6007x over previous
//
#include <hip/hip_runtime.h>
#include <hip/hip_bf16.h>

#define NFREQ 50
#define EMBD  10

// sin/cos of x (radians) via HW v_sin/v_cos. HW takes revolutions; reduce
// into [0,1) with v_fract first (exact by periodicity).
__device__ __forceinline__ void fast_sincos2pi(float x, float& s, float& c) {
    float r = x * 0.15915494309189535f;       // x / (2*pi)
    r = __builtin_amdgcn_fractf(r);           // [0,1): safe domain
    s = __builtin_amdgcn_sinf(r);             // sin(2*pi*r)
    c = __builtin_amdgcn_cosf(r);             // cos(2*pi*r)
}

__global__ void zero_ws(float4* p, int n4) {
    int t = blockIdx.x * blockDim.x + threadIdx.x;
    float4 z = make_float4(0.f, 0.f, 0.f, 0.f);
    for (int i = t; i < n4; i += gridDim.x * blockDim.x) p[i] = z;
}

__global__ __launch_bounds__(256) void frag_kernel(
    const float2* __restrict__ coords, const int* __restrict__ cgix,
    const float* __restrict__ W1, const float* __restrict__ b1,
    const float* __restrict__ W2, const float* __restrict__ b2,
    float* __restrict__ pooled, int n)
{
    int t = blockIdx.x * blockDim.x + threadIdx.x;
    int lane = threadIdx.x & 63;
    // n is a multiple of 64 -> waves are fully active or fully inactive.
    // Guard generically anyway: inactive lanes get seg = -1 and never write.
    bool active = t < n;
    if (__builtin_amdgcn_ballot_w64(active) == 0ull) return;

    float2 cc = active ? coords[t] : make_float2(0.f, 0.f);
    int seg = active ? cgix[t] : -1;

    float e[EMBD];   // will hold emb, then scanned partial sums
    {
        float acc[EMBD];
        #pragma unroll
        for (int j = 0; j < EMBD; ++j) acc[j] = b1[j];

        // enc[d*100 + 2i] = sin(c_d * f_{i+1}); enc[.. +1] = cos(...)
        #pragma unroll
        for (int d = 0; d < 2; ++d) {
            float cd = d ? cc.y : cc.x;
            #pragma unroll
            for (int i = 0; i < NFREQ; ++i) {
                // 1000^(-2(i+1)/50): folds to a compile-time literal
                float f = __builtin_exp2f(-0.39863137138648348f * (float)(i + 1));
                float s, co;
                fast_sincos2pi(cd * f, s, co);
                const float* w = W1 + (d * 2 * NFREQ + 2 * i) * EMBD; // uniform -> s_load
                #pragma unroll
                for (int j = 0; j < EMBD; ++j) acc[j] = fmaf(s,  w[j],        acc[j]);
                #pragma unroll
                for (int j = 0; j < EMBD; ++j) acc[j] = fmaf(co, w[EMBD + j], acc[j]);
            }
        }
        // sigmoid
        float h[EMBD];
        #pragma unroll
        for (int j = 0; j < EMBD; ++j)
            h[j] = __builtin_amdgcn_rcpf(1.0f + __expf(-acc[j]));
        // layer 2: e = h @ W2 + b2
        #pragma unroll
        for (int j = 0; j < EMBD; ++j) e[j] = b2[j];
        #pragma unroll
        for (int m = 0; m < EMBD; ++m) {
            #pragma unroll
            for (int j = 0; j < EMBD; ++j) e[j] = fmaf(h[m], W2[m * EMBD + j], e[j]);
        }
    }

    // ---- wave-level segmented inclusive scan over sorted seg ids ----
    #pragma unroll
    for (int d = 1; d < 64; d <<= 1) {
        int sup = __shfl_up(seg, d, 64);
        bool ok = (lane >= d) && (sup == seg);
        #pragma unroll
        for (int j = 0; j < EMBD; ++j) {
            float u = __shfl_up(e[j], d, 64);
            e[j] += ok ? u : 0.0f;
        }
    }

    // run tail = last lane of each equal-seg run within the wave
    int seg_next = __shfl_down(seg, 1, 64);
    bool writer = active && ((lane == 63) || (seg_next != seg));
    int first_seg = __shfl(seg, 0, 64);
    int last_seg  = __shfl(seg, 63, 64);

    if (writer) {
        float* p = pooled + (long)seg * EMBD;
        if (seg == first_seg || seg == last_seg) {
            // may be shared with neighboring waves -> native f32 atomic (no CAS)
            #pragma unroll
            for (int j = 0; j < EMBD; ++j) unsafeAtomicAdd(p + j, e[j]);
        } else {
            // segment entirely inside this wave (global sort) -> plain store
            #pragma unroll
            for (int j = 0; j < EMBD; ++j) p[j] = e[j];
        }
    }
}

__global__ __launch_bounds__(256) void expr_kernel(
    const float* __restrict__ pooled,
    const float* __restrict__ We1, const float* __restrict__ be1,
    const float* __restrict__ We2, const float* __restrict__ be2,
    float* __restrict__ out, int nseg)
{
    int t = blockIdx.x * blockDim.x + threadIdx.x;
    if (t >= nseg) return;
    const float* p = pooled + (long)t * EMBD;
    float x[EMBD];
    #pragma unroll
    for (int j = 0; j < EMBD; ++j) x[j] = p[j];
    float o = be2[0];
    #pragma unroll
    for (int j = 0; j < EMBD; ++j) {
        float a = be1[j];
        #pragma unroll
        for (int m = 0; m < EMBD; ++m) a = fmaf(x[m], We1[m * EMBD + j], a);
        float hj = __builtin_amdgcn_rcpf(1.0f + __expf(-a));
        o = fmaf(hj, We2[j], o);
    }
    out[t] = o;   // reference output dtype is float32
}

extern "C" void kernel_launch(void* const* d_in, const int* in_sizes, int n_in,
                              void* d_out, int out_size, void* d_ws, size_t ws_size,
                              hipStream_t stream) {
    const float2* coords = (const float2*)d_in[0];
    const int*    cgix   = (const int*)d_in[1];
    const float*  W1     = (const float*)d_in[4];
    const float*  b1     = (const float*)d_in[5];
    const float*  W2     = (const float*)d_in[6];
    const float*  b2     = (const float*)d_in[7];
    const float*  We1    = (const float*)d_in[8];
    const float*  be1    = (const float*)d_in[9];
    const float*  We2    = (const float*)d_in[10];
    const float*  be2    = (const float*)d_in[11];
    float*        out    = (float*)d_out;

    int n    = in_sizes[0] / 2;      // 1,000,000 fragments
    int nseg = out_size;             // 250,000 = cells*genes
    float* pooled = (float*)d_ws;    // nseg*10 f32 = 10 MB scratch

    // ws is poisoned (0xAA) and not re-poisoned between replays: zero every call
    int n4 = (nseg * EMBD) / 4;      // 2.5M floats, divisible by 4
    zero_ws<<<1024, 256, 0, stream>>>((float4*)pooled, n4);

    frag_kernel<<<(n + 255) / 256, 256, 0, stream>>>(coords, cgix, W1, b1, W2, b2,
                                                     pooled, n);
    expr_kernel<<<(nseg + 255) / 256, 256, 0, stream>>>(pooled, We1, be1, We2, be2,
                                                        out, nseg);
}

// Round 4
// 61.780 us; speedup vs baseline: 9.8688x; 1.4951x over previous
//
#include <hip/hip_runtime.h>
#include <hip/hip_bf16.h>

#define NFREQ 50
#define EMBD  10

typedef __attribute__((ext_vector_type(8))) short short8;   // 8 bf16 (4 VGPRs)
typedef __attribute__((ext_vector_type(4))) float f32x4;    // MFMA accumulator

__device__ __forceinline__ unsigned short bf16b(float x) {
    union { __hip_bfloat16 b; unsigned short u; } c;
    c.b = __float2bfloat16(x);          // RNE convert on gfx950
    return c.u;
}

__global__ void zero_ws(float4* p, int n4) {
    int t = blockIdx.x * blockDim.x + threadIdx.x;
    float4 z = make_float4(0.f, 0.f, 0.f, 0.f);
    for (int i = t; i < n4; i += gridDim.x * blockDim.x) p[i] = z;
}

__global__ __launch_bounds__(256) void frag_kernel(
    const float2* __restrict__ coords, const int* __restrict__ cgix,
    const float* __restrict__ W1, const float* __restrict__ b1,
    const float* __restrict__ W2, const float* __restrict__ b2,
    float* __restrict__ pooled, int n)
{
    // W1 (bf16) pre-permuted into B-fragment order: [kt][g][col][e], e = k-minor
    __shared__ unsigned short w1lds[7 * 4 * 16 * 8];         // 7168 B
    __shared__ float hbuf[4][64][13];                        // 13312 B, pad 13 vs bank stride

    const int tid  = threadIdx.x;
    const int wid  = tid >> 6;
    const int lane = tid & 63;
    const int grp  = lane >> 4;
    const int col  = lane & 15;
    const int wavebase = blockIdx.x * 256 + wid * 64;
    const int t = wavebase + lane;
    const bool active = t < n;

    // ---- stage W1 into LDS (one-time, cooperative; zero-pad k>=200, col>=10) ----
    #pragma unroll
    for (int it = 0; it < 14; ++it) {                        // 3584 elems / 256 thr
        int idx = it * 256 + tid;
        int e = idx & 7, c = (idx >> 3) & 15, g = (idx >> 7) & 3, kt = idx >> 9;
        int k = kt * 32 + g * 8 + e;
        float w = (k < 2 * NFREQ * 2 && c < EMBD) ? W1[k * EMBD + c] : 0.f;
        w1lds[idx] = bf16b(w);
    }
    __syncthreads();

    // B fragments: lane holds B[k = kt*32 + grp*8 + e][col], 7 x ds_read_b128
    short8 Bf[7];
    #pragma unroll
    for (int kt = 0; kt < 7; ++kt)
        Bf[kt] = *reinterpret_cast<const short8*>(&w1lds[((kt * 4 + grp) * 16 + col) * 8]);

    // per-lane frequencies (pre-scaled by 1/2pi); pair p covers enc cols k0,k0+1
    float freq[7][4];
    #pragma unroll
    for (int kt = 0; kt < 7; ++kt) {
        #pragma unroll
        for (int p = 0; p < 4; ++p) {
            int k0  = kt * 32 + grp * 8 + 2 * p;
            int d   = (k0 >= 100) ? 1 : 0;
            int ip1 = ((k0 - 100 * d) >> 1) + 1;             // i+1 in 1..50 (garbage ok in pad)
            freq[kt][p] = __builtin_exp2f(-0.39863137138648348f * (float)ip1)
                        * 0.15915494309189535f;
        }
    }

    float2 cc = active ? coords[t] : make_float2(0.f, 0.f);
    int   seg = active ? cgix[t] : -1;
    float b1v = (col < EMBD) ? b1[col] : 0.f;

    // ---- layer 1 as MFMA: 4 sub-tiles x 7 k-tiles ----
    #pragma unroll
    for (int s = 0; s < 4; ++s) {
        // coords of the fragment in A-row (l&15) of sub-tile s
        float cx = __shfl(cc.x, s * 16 + col, 64);
        float cy = __shfl(cc.y, s * 16 + col, 64);
        f32x4 acc = {b1v, b1v, b1v, b1v};                    // bias baked into C
        #pragma unroll
        for (int kt = 0; kt < 7; ++kt) {
            short8 a;
            #pragma unroll
            for (int p = 0; p < 4; ++p) {
                float cde;
                if      (kt < 3) cde = cx;                   // k0 < 100 always
                else if (kt > 3) cde = cy;                   // k0 >= 128 always
                else             cde = (grp * 8 + 2 * p >= 4) ? cy : cx;  // kt==3 mixed
                float r  = __builtin_amdgcn_fractf(cde * freq[kt][p]);
                a[2*p]   = (short)bf16b(__builtin_amdgcn_sinf(r));
                a[2*p+1] = (short)bf16b(__builtin_amdgcn_cosf(r));
            }
            acc = __builtin_amdgcn_mfma_f32_16x16x32_bf16(a, Bf[kt], acc, 0, 0, 0);
        }
        // C layout: col=lane&15, row=(lane>>4)*4+reg (verified) -> LDS transpose
        if (col < EMBD) {
            #pragma unroll
            for (int r = 0; r < 4; ++r)
                hbuf[wid][s * 16 + grp * 4 + r][col] = acc[r];
        }
    }
    __syncthreads();    // no early returns anywhere -> barrier is safe

    // ---- back to thread-per-fragment: sigmoid + layer 2 ----
    float h[EMBD];
    #pragma unroll
    for (int j = 0; j < EMBD; ++j) {
        float a = hbuf[wid][lane][j];
        h[j] = __builtin_amdgcn_rcpf(1.0f + __expf(-a));
    }
    float e[EMBD];
    #pragma unroll
    for (int j = 0; j < EMBD; ++j) e[j] = b2[j];
    #pragma unroll
    for (int m = 0; m < EMBD; ++m) {
        #pragma unroll
        for (int j = 0; j < EMBD; ++j) e[j] = fmaf(h[m], W2[m * EMBD + j], e[j]);
    }

    // ---- wave-level segmented inclusive scan over sorted seg ids ----
    #pragma unroll
    for (int d = 1; d < 64; d <<= 1) {
        int sup = __shfl_up(seg, d, 64);
        bool ok = (lane >= d) && (sup == seg);
        #pragma unroll
        for (int j = 0; j < EMBD; ++j) {
            float u = __shfl_up(e[j], d, 64);
            e[j] += ok ? u : 0.0f;
        }
    }

    int seg_next = __shfl_down(seg, 1, 64);
    bool writer = active && ((lane == 63) || (seg_next != seg));
    int first_seg = __shfl(seg, 0, 64);
    int last_seg  = __shfl(seg, 63, 64);

    if (writer) {
        float* p = pooled + (long)seg * EMBD;
        if (seg == first_seg || seg == last_seg) {
            // may span waves -> native f32 atomic (no CAS)
            #pragma unroll
            for (int j = 0; j < EMBD; ++j) unsafeAtomicAdd(p + j, e[j]);
        } else {
            // segment entirely inside this wave -> plain store
            #pragma unroll
            for (int j = 0; j < EMBD; ++j) p[j] = e[j];
        }
    }
}

__global__ __launch_bounds__(256) void expr_kernel(
    const float* __restrict__ pooled,
    const float* __restrict__ We1, const float* __restrict__ be1,
    const float* __restrict__ We2, const float* __restrict__ be2,
    float* __restrict__ out, int nseg)
{
    int t = blockIdx.x * blockDim.x + threadIdx.x;
    if (t >= nseg) return;
    const float* p = pooled + (long)t * EMBD;
    float x[EMBD];
    #pragma unroll
    for (int j = 0; j < EMBD; ++j) x[j] = p[j];
    float o = be2[0];
    #pragma unroll
    for (int j = 0; j < EMBD; ++j) {
        float a = be1[j];
        #pragma unroll
        for (int m = 0; m < EMBD; ++m) a = fmaf(x[m], We1[m * EMBD + j], a);
        float hj = __builtin_amdgcn_rcpf(1.0f + __expf(-a));
        o = fmaf(hj, We2[j], o);
    }
    out[t] = o;   // reference output dtype is float32
}

extern "C" void kernel_launch(void* const* d_in, const int* in_sizes, int n_in,
                              void* d_out, int out_size, void* d_ws, size_t ws_size,
                              hipStream_t stream) {
    const float2* coords = (const float2*)d_in[0];
    const int*    cgix   = (const int*)d_in[1];
    const float*  W1     = (const float*)d_in[4];
    const float*  b1     = (const float*)d_in[5];
    const float*  W2     = (const float*)d_in[6];
    const float*  b2     = (const float*)d_in[7];
    const float*  We1    = (const float*)d_in[8];
    const float*  be1    = (const float*)d_in[9];
    const float*  We2    = (const float*)d_in[10];
    const float*  be2    = (const float*)d_in[11];
    float*        out    = (float*)d_out;

    int n    = in_sizes[0] / 2;      // 1,000,000 fragments
    int nseg = out_size;             // 250,000 = cells*genes
    float* pooled = (float*)d_ws;    // nseg*10 f32 = 10 MB scratch

    // ws is poisoned (0xAA) and not re-poisoned between replays: zero every call
    int n4 = (nseg * EMBD) / 4;
    zero_ws<<<1024, 256, 0, stream>>>((float4*)pooled, n4);

    frag_kernel<<<(n + 255) / 256, 256, 0, stream>>>(coords, cgix, W1, b1, W2, b2,
                                                     pooled, n);
    expr_kernel<<<(nseg + 255) / 256, 256, 0, stream>>>(pooled, We1, be1, We2, be2,
                                                        out, nseg);
}

// Round 5
// 55.086 us; speedup vs baseline: 11.0681x; 1.1215x over previous
//
#include <hip/hip_runtime.h>
#include <hip/hip_bf16.h>

#define NFREQ 50
#define EMBD  10

typedef __attribute__((ext_vector_type(8))) short short8;   // 8 bf16 (4 VGPRs)
typedef __attribute__((ext_vector_type(4))) float f32x4;    // MFMA accumulator

__device__ __forceinline__ unsigned short bf16b(float x) {
    union { __hip_bfloat16 b; unsigned short u; } c;
    c.b = __float2bfloat16(x);          // RNE convert on gfx950
    return c.u;
}

// C_TAB[kt][p] = r^(16*kt+p+1), r = 1000^(-2/50) = 10^(-0.12)
// full freq for slot (kt,grp,p): x-region r^(16kt+4grp+p+1) = C*G(grp);
// y-region adds r^-50 = 1e6 exactly (folded into ay).
__device__ const float C_TAB[7][4] = {
    {7.58577575029184e-1f, 5.75439937337157e-1f, 4.36515832240166e-1f, 3.31131121482591e-1f},
    {9.12010839355910e-3f, 6.91830970918936e-3f, 5.24807460249773e-3f, 3.98107170553497e-3f},
    {1.09647819614318e-4f, 8.31763771102671e-5f, 6.30957344480193e-5f, 4.78630092322638e-5f},
    {1.31825673855641e-6f, 1.00000000000000e-6f, 7.58577575029184e-7f, 5.75439937337157e-7f},
    {1.58489319246111e-8f, 1.20226443461741e-8f, 9.12010839355910e-9f, 6.91830970918936e-9f},
    {1.90546071796325e-10f,1.44543977074593e-10f,1.09647819614318e-10f,8.31763771102671e-11f},
    {2.29086765276777e-12f,1.73780082874938e-12f,1.31825673855641e-12f,1.00000000000000e-12f}
};

__global__ void zero_ws(float4* p, int n4) {
    int t = blockIdx.x * blockDim.x + threadIdx.x;
    float4 z = make_float4(0.f, 0.f, 0.f, 0.f);
    for (int i = t; i < n4; i += gridDim.x * blockDim.x) p[i] = z;
}

__global__ __launch_bounds__(256) void frag_kernel(
    const float2* __restrict__ coords, const int* __restrict__ cgix,
    const float* __restrict__ W1, const float* __restrict__ b1,
    const float* __restrict__ W2, const float* __restrict__ b2,
    float* __restrict__ pooled, int n)
{
    // W1 (bf16) pre-permuted into B-fragment order: [kt][g][col][e], e = k-minor
    __shared__ unsigned short w1lds[7 * 4 * 16 * 8];         // 7168 B
    __shared__ float hbuf[4][64][13];                        // wave-private slices

    const int tid  = threadIdx.x;
    const int wid  = tid >> 6;
    const int lane = tid & 63;
    const int grp  = lane >> 4;
    const int col  = lane & 15;
    const int t = blockIdx.x * 256 + wid * 64 + lane;
    const bool active = t < n;

    // ---- stage W1 into LDS (one-time, cooperative; zero-pad k>=200, col>=10) ----
    #pragma unroll
    for (int it = 0; it < 14; ++it) {                        // 3584 elems / 256 thr
        int idx = it * 256 + tid;
        int e = idx & 7, c = (idx >> 3) & 15, g = (idx >> 7) & 3, kt = idx >> 9;
        int k = kt * 32 + g * 8 + e;
        float w = (k < 2 * NFREQ * 2 && c < EMBD) ? W1[k * EMBD + c] : 0.f;
        w1lds[idx] = bf16b(w);
    }
    __syncthreads();   // staged weights shared across all 4 waves

    // B fragments: lane holds B[k = kt*32 + grp*8 + e][col], 7 x ds_read_b128
    short8 Bf[7];
    #pragma unroll
    for (int kt = 0; kt < 7; ++kt)
        Bf[kt] = *reinterpret_cast<const short8*>(&w1lds[((kt * 4 + grp) * 16 + col) * 8]);

    // per-lane freq factor G(grp) = r^(4grp), pre-scaled by 1/2pi (and 1e6 for y)
    float G = (grp == 0) ? 1.0f
            : (grp == 1) ? 3.31131121482591e-1f
            : (grp == 2) ? 1.09647819614318e-1f
                         : 3.63078054770101e-2f;
    float gi = G * 0.15915494309189535f;     // x-coord multiplier
    float gy = gi * 1.0e6f;                  // y-coord multiplier (r^-50 = 1e6)

    float2 cc = active ? coords[t] : make_float2(0.f, 0.f);
    int   seg = active ? cgix[t] : -1;
    float b1v = (col < EMBD) ? b1[col] : 0.f;

    // ---- layer 1 as MFMA: 4 sub-tiles x 7 k-tiles ----
    #pragma unroll
    for (int s = 0; s < 4; ++s) {
        float cx = __shfl(cc.x, s * 16 + col, 64);
        float cy = __shfl(cc.y, s * 16 + col, 64);
        float ax  = cx * gi;
        float ay  = cy * gy;
        float a01 = (grp == 0) ? ax : ay;    // kt==3, p<2: x only for grp 0
        f32x4 acc = {b1v, b1v, b1v, b1v};    // bias baked into C
        #pragma unroll
        for (int kt = 0; kt < 7; ++kt) {
            short8 a;
            #pragma unroll
            for (int p = 0; p < 4; ++p) {
                float base;
                if      (kt < 3) base = ax;
                else if (kt > 3) base = ay;
                else             base = (p < 2) ? a01 : ay;
                float rr = __builtin_amdgcn_fractf(base * C_TAB[kt][p]);
                a[2*p]   = (short)bf16b(__builtin_amdgcn_sinf(rr));
                a[2*p+1] = (short)bf16b(__builtin_amdgcn_cosf(rr));
            }
            acc = __builtin_amdgcn_mfma_f32_16x16x32_bf16(a, Bf[kt], acc, 0, 0, 0);
        }
        // C layout: lane holds D[frag = grp*4+r][j = col] -> transpose via LDS
        if (col < EMBD) {
            #pragma unroll
            for (int r = 0; r < 4; ++r)
                hbuf[wid][s * 16 + grp * 4 + r][col] = acc[r];
        }
    }
    // hbuf is wave-private: wave-lockstep visibility after LDS drain (no block barrier)
    asm volatile("s_waitcnt lgkmcnt(0)" ::: "memory");
    __builtin_amdgcn_sched_barrier(0);

    // ---- back to thread-per-fragment: sigmoid + layer 2 ----
    float h[EMBD];
    #pragma unroll
    for (int j = 0; j < EMBD; ++j) {
        float a = hbuf[wid][lane][j];
        h[j] = __builtin_amdgcn_rcpf(1.0f + __expf(-a));
    }
    float e[EMBD];
    #pragma unroll
    for (int j = 0; j < EMBD; ++j) e[j] = b2[j];
    #pragma unroll
    for (int m = 0; m < EMBD; ++m) {
        #pragma unroll
        for (int j = 0; j < EMBD; ++j) e[j] = fmaf(h[m], W2[m * EMBD + j], e[j]);
    }

    // ---- wave-level segmented inclusive scan (sorted seg ids) with early exit:
    // sorted => if no lane merges at distance d, none merges at any larger d.
    for (int d = 1; d < 64; d <<= 1) {
        int sup = __shfl_up(seg, d, 64);
        bool ok = (lane >= d) && (sup == seg);
        if (__builtin_amdgcn_ballot_w64(ok) == 0ull) break;   // wave-uniform
        #pragma unroll
        for (int j = 0; j < EMBD; ++j) {
            float u = __shfl_up(e[j], d, 64);
            e[j] += ok ? u : 0.0f;
        }
    }

    int seg_next = __shfl_down(seg, 1, 64);
    bool writer = active && ((lane == 63) || (seg_next != seg));
    int first_seg = __shfl(seg, 0, 64);
    int last_seg  = __shfl(seg, 63, 64);

    if (writer) {
        float* p = pooled + (long)seg * EMBD;
        if (seg == first_seg || seg == last_seg) {
            // may span waves -> native f32 atomic (no CAS)
            #pragma unroll
            for (int j = 0; j < EMBD; ++j) unsafeAtomicAdd(p + j, e[j]);
        } else {
            // segment entirely inside this wave -> plain store
            #pragma unroll
            for (int j = 0; j < EMBD; ++j) p[j] = e[j];
        }
    }
}

__global__ __launch_bounds__(256) void expr_kernel(
    const float* __restrict__ pooled,
    const float* __restrict__ We1, const float* __restrict__ be1,
    const float* __restrict__ We2, const float* __restrict__ be2,
    float* __restrict__ out, int nseg)
{
    int t = blockIdx.x * blockDim.x + threadIdx.x;
    if (t >= nseg) return;
    const float* p = pooled + (long)t * EMBD;
    float x[EMBD];
    #pragma unroll
    for (int j = 0; j < EMBD; ++j) x[j] = p[j];
    float o = be2[0];
    #pragma unroll
    for (int j = 0; j < EMBD; ++j) {
        float a = be1[j];
        #pragma unroll
        for (int m = 0; m < EMBD; ++m) a = fmaf(x[m], We1[m * EMBD + j], a);
        float hj = __builtin_amdgcn_rcpf(1.0f + __expf(-a));
        o = fmaf(hj, We2[j], o);
    }
    out[t] = o;   // reference output dtype is float32
}

extern "C" void kernel_launch(void* const* d_in, const int* in_sizes, int n_in,
                              void* d_out, int out_size, void* d_ws, size_t ws_size,
                              hipStream_t stream) {
    const float2* coords = (const float2*)d_in[0];
    const int*    cgix   = (const int*)d_in[1];
    const float*  W1     = (const float*)d_in[4];
    const float*  b1     = (const float*)d_in[5];
    const float*  W2     = (const float*)d_in[6];
    const float*  b2     = (const float*)d_in[7];
    const float*  We1    = (const float*)d_in[8];
    const float*  be1    = (const float*)d_in[9];
    const float*  We2    = (const float*)d_in[10];
    const float*  be2    = (const float*)d_in[11];
    float*        out    = (float*)d_out;

    int n    = in_sizes[0] / 2;      // 1,000,000 fragments
    int nseg = out_size;             // 250,000 = cells*genes
    float* pooled = (float*)d_ws;    // nseg*10 f32 = 10 MB scratch

    // ws is poisoned (0xAA) and not re-poisoned between replays: zero every call
    int n4 = (nseg * EMBD) / 4;
    zero_ws<<<1024, 256, 0, stream>>>((float4*)pooled, n4);

    frag_kernel<<<(n + 255) / 256, 256, 0, stream>>>(coords, cgix, W1, b1, W2, b2,
                                                     pooled, n);
    expr_kernel<<<(nseg + 255) / 256, 256, 0, stream>>>(pooled, We1, be1, We2, be2,
                                                        out, nseg);
}

// Round 6
// 54.837 us; speedup vs baseline: 11.1183x; 1.0045x over previous
//
#include <hip/hip_runtime.h>
#include <hip/hip_bf16.h>

#define NFREQ 50
#define EMBD  10

typedef __attribute__((ext_vector_type(8))) short short8;   // 8 bf16 (4 VGPRs)
typedef __attribute__((ext_vector_type(4))) float f32x4;    // MFMA accumulator

__device__ __forceinline__ unsigned short bf16b(float x) {
    union { __hip_bfloat16 b; unsigned short u; } c;
    c.b = __float2bfloat16(x);          // RNE convert on gfx950
    return c.u;
}

// C_TAB[kt][p] = r^(16*kt+p+1), r = 1000^(-2/50) = 10^(-0.12)
// slot (kt,grp,p): freq = C*G(grp), y-region multiplies by r^-50 = 1e6 (in ay).
__device__ const float C_TAB[7][4] = {
    {7.58577575029184e-1f, 5.75439937337157e-1f, 4.36515832240166e-1f, 3.31131121482591e-1f},
    {9.12010839355910e-3f, 6.91830970918936e-3f, 5.24807460249773e-3f, 3.98107170553497e-3f},
    {1.09647819614318e-4f, 8.31763771102671e-5f, 6.30957344480193e-5f, 4.78630092322638e-5f},
    {1.31825673855641e-6f, 1.00000000000000e-6f, 7.58577575029184e-7f, 5.75439937337157e-7f},
    {1.58489319246111e-8f, 1.20226443461741e-8f, 9.12010839355910e-9f, 6.91830970918936e-9f},
    {1.90546071796325e-10f,1.44543977074593e-10f,1.09647819614318e-10f,8.31763771102671e-11f},
    {2.29086765276777e-12f,1.73780082874938e-12f,1.31825673855641e-12f,1.00000000000000e-12f}
};

// compile-time: slot skips trans (min exponent over grp >= 34 -> |phase| <= ~0.45 rad)
__device__ __forceinline__ constexpr bool lin_slot(int kt, int p) {
    return (kt == 2 && p >= 1) || (kt == 5 && p == 3) || (kt == 6);
}

__global__ void zero_ws(float4* p, int n4) {
    int t = blockIdx.x * blockDim.x + threadIdx.x;
    float4 z = make_float4(0.f, 0.f, 0.f, 0.f);
    for (int i = t; i < n4; i += gridDim.x * blockDim.x) p[i] = z;
}

__global__ __launch_bounds__(256) void frag_kernel(
    const float2* __restrict__ coords, const int* __restrict__ cgix,
    const float* __restrict__ W1, const float* __restrict__ b1,
    const float* __restrict__ W2, const float* __restrict__ b2,
    float* __restrict__ pooled, int n)
{
    // W1 (bf16) pre-permuted into B-fragment order: [kt][g][col][e], e = k-minor
    __shared__ unsigned short w1lds[7 * 4 * 16 * 8];         // 7168 B
    __shared__ float hbuf[4][64][11];                        // 11264 B; total 18432 B
                                                             // (< 160K/8 incl. any resv)
    const int tid  = threadIdx.x;
    const int wid  = tid >> 6;
    const int lane = tid & 63;
    const int grp  = lane >> 4;
    const int col  = lane & 15;
    const int t = blockIdx.x * 256 + wid * 64 + lane;
    const bool active = t < n;

    // ---- stage W1 into LDS (one-time, cooperative; zero-pad k>=200, col>=10) ----
    #pragma unroll
    for (int it = 0; it < 14; ++it) {                        // 3584 elems / 256 thr
        int idx = it * 256 + tid;
        int e = idx & 7, c = (idx >> 3) & 15, g = (idx >> 7) & 3, kt = idx >> 9;
        int k = kt * 32 + g * 8 + e;
        float w = (k < 2 * NFREQ * 2 && c < EMBD) ? W1[k * EMBD + c] : 0.f;
        w1lds[idx] = bf16b(w);
    }
    __syncthreads();   // staged weights shared across all 4 waves

    // B fragments: lane holds B[k = kt*32 + grp*8 + e][col], 7 x ds_read_b128
    short8 Bf[7];
    #pragma unroll
    for (int kt = 0; kt < 7; ++kt)
        Bf[kt] = *reinterpret_cast<const short8*>(&w1lds[((kt * 4 + grp) * 16 + col) * 8]);

    // per-lane freq factor G(grp) = r^(4grp), pre-scaled by 1/2pi (and 1e6 for y)
    float G = (grp == 0) ? 1.0f
            : (grp == 1) ? 3.31131121482591e-1f
            : (grp == 2) ? 1.09647819614318e-1f
                         : 3.63078054770101e-2f;
    float gi = G * 0.15915494309189535f;     // x-coord multiplier
    float gy = gi * 1.0e6f;                  // y-coord multiplier (r^-50 = 1e6)

    float2 cc = active ? coords[t] : make_float2(0.f, 0.f);
    int   seg = active ? cgix[t] : -1;
    float b1v = (col < EMBD) ? b1[col] : 0.f;

    // ---- layer 1 as MFMA: 4 sub-tiles x 7 k-tiles ----
    #pragma unroll
    for (int s = 0; s < 4; ++s) {
        float cx = __shfl(cc.x, s * 16 + col, 64);
        float cy = __shfl(cc.y, s * 16 + col, 64);
        float ax  = cx * gi;
        float ay  = cy * gy;
        float a01 = (grp == 0) ? ax : ay;    // kt==3, p<2: x only for grp 0
        f32x4 acc = {b1v, b1v, b1v, b1v};    // bias baked into C
        #pragma unroll
        for (int kt = 0; kt < 7; ++kt) {
            short8 a;
            #pragma unroll
            for (int p = 0; p < 4; ++p) {
                float base;
                if      (kt < 3) base = ax;
                else if (kt > 3) base = ay;
                else             base = (p < 2) ? a01 : ay;
                if (lin_slot(kt, p)) {
                    // |phi| <= ~0.45 rad even at 5.4-sigma coords:
                    // sin = phi(1 - phi^2/6), cos = 1 - phi^2/2
                    float phi = base * (C_TAB[kt][p] * 6.28318530717958647f);
                    float t2  = phi * phi;
                    float sv  = phi * fmaf(t2, -0.16666666666f, 1.0f);
                    float cv  = fmaf(t2, -0.5f, 1.0f);
                    if (kt == 6 && grp != 0) { sv = 0.f; cv = 0.f; }  // K-padding
                    a[2*p]   = (short)bf16b(sv);
                    a[2*p+1] = (short)bf16b(cv);
                } else {
                    float rr = __builtin_amdgcn_fractf(base * C_TAB[kt][p]);
                    a[2*p]   = (short)bf16b(__builtin_amdgcn_sinf(rr));
                    a[2*p+1] = (short)bf16b(__builtin_amdgcn_cosf(rr));
                }
            }
            acc = __builtin_amdgcn_mfma_f32_16x16x32_bf16(a, Bf[kt], acc, 0, 0, 0);
        }
        // C layout: lane holds D[frag = grp*4+r][j = col] -> transpose via LDS
        if (col < EMBD) {
            #pragma unroll
            for (int r = 0; r < 4; ++r)
                hbuf[wid][s * 16 + grp * 4 + r][col] = acc[r];
        }
    }
    // hbuf is wave-private: wave-lockstep visibility after LDS drain (no block barrier)
    asm volatile("s_waitcnt lgkmcnt(0)" ::: "memory");
    __builtin_amdgcn_sched_barrier(0);

    // ---- back to thread-per-fragment: sigmoid + layer 2 ----
    float h[EMBD];
    #pragma unroll
    for (int j = 0; j < EMBD; ++j) {
        float a = hbuf[wid][lane][j];
        h[j] = __builtin_amdgcn_rcpf(1.0f + __expf(-a));
    }
    float e[EMBD];
    #pragma unroll
    for (int j = 0; j < EMBD; ++j) e[j] = b2[j];
    #pragma unroll
    for (int m = 0; m < EMBD; ++m) {
        #pragma unroll
        for (int j = 0; j < EMBD; ++j) e[j] = fmaf(h[m], W2[m * EMBD + j], e[j]);
    }

    // ---- wave-level segmented inclusive scan (sorted seg ids) with early exit ----
    for (int d = 1; d < 64; d <<= 1) {
        int sup = __shfl_up(seg, d, 64);
        bool ok = (lane >= d) && (sup == seg);
        if (__builtin_amdgcn_ballot_w64(ok) == 0ull) break;   // wave-uniform
        #pragma unroll
        for (int j = 0; j < EMBD; ++j) {
            float u = __shfl_up(e[j], d, 64);
            e[j] += ok ? u : 0.0f;
        }
    }

    int seg_next = __shfl_down(seg, 1, 64);
    bool writer = active && ((lane == 63) || (seg_next != seg));
    int first_seg = __shfl(seg, 0, 64);
    int last_seg  = __shfl(seg, 63, 64);

    if (writer) {
        float* p = pooled + (long)seg * EMBD;
        if (seg == first_seg || seg == last_seg) {
            // may span waves -> native f32 atomic (no CAS)
            #pragma unroll
            for (int j = 0; j < EMBD; ++j) unsafeAtomicAdd(p + j, e[j]);
        } else {
            // segment entirely inside this wave -> plain store
            #pragma unroll
            for (int j = 0; j < EMBD; ++j) p[j] = e[j];
        }
    }
}

__global__ __launch_bounds__(256) void expr_kernel(
    const float* __restrict__ pooled,
    const float* __restrict__ We1, const float* __restrict__ be1,
    const float* __restrict__ We2, const float* __restrict__ be2,
    float* __restrict__ out, int nseg)
{
    int t = blockIdx.x * blockDim.x + threadIdx.x;
    if (t >= nseg) return;
    const float2* p2 = (const float2*)(pooled + (long)t * EMBD);  // 8B-aligned (40B rows)
    float x[EMBD];
    #pragma unroll
    for (int j = 0; j < EMBD / 2; ++j) {
        float2 v = p2[j];
        x[2*j] = v.x; x[2*j+1] = v.y;
    }
    float o = be2[0];
    #pragma unroll
    for (int j = 0; j < EMBD; ++j) {
        float a = be1[j];
        #pragma unroll
        for (int m = 0; m < EMBD; ++m) a = fmaf(x[m], We1[m * EMBD + j], a);
        float hj = __builtin_amdgcn_rcpf(1.0f + __expf(-a));
        o = fmaf(hj, We2[j], o);
    }
    out[t] = o;   // reference output dtype is float32
}

extern "C" void kernel_launch(void* const* d_in, const int* in_sizes, int n_in,
                              void* d_out, int out_size, void* d_ws, size_t ws_size,
                              hipStream_t stream) {
    const float2* coords = (const float2*)d_in[0];
    const int*    cgix   = (const int*)d_in[1];
    const float*  W1     = (const float*)d_in[4];
    const float*  b1     = (const float*)d_in[5];
    const float*  W2     = (const float*)d_in[6];
    const float*  b2     = (const float*)d_in[7];
    const float*  We1    = (const float*)d_in[8];
    const float*  be1    = (const float*)d_in[9];
    const float*  We2    = (const float*)d_in[10];
    const float*  be2    = (const float*)d_in[11];
    float*        out    = (float*)d_out;

    int n    = in_sizes[0] / 2;      // 1,000,000 fragments
    int nseg = out_size;             // 250,000 = cells*genes
    float* pooled = (float*)d_ws;    // nseg*10 f32 = 10 MB scratch

    // ws is poisoned (0xAA) and not re-poisoned between replays: zero every call
    int n4 = (nseg * EMBD) / 4;                       // 625,000 float4
    int zb = (n4 + 255) / 256;                        // one element per thread
    zero_ws<<<zb, 256, 0, stream>>>((float4*)pooled, n4);

    frag_kernel<<<(n + 255) / 256, 256, 0, stream>>>(coords, cgix, W1, b1, W2, b2,
                                                     pooled, n);
    expr_kernel<<<(nseg + 255) / 256, 256, 0, stream>>>(pooled, We1, be1, We2, be2,
                                                        out, nseg);
}